// Round 1
// baseline (6549.668 us; speedup 1.0000x reference)
//
#include <hip/hip_runtime.h>
#include <hip/hip_bf16.h>

// LSTM decoder: H=1024, B=4096, T=128, IN=1.
// Recurrence per step: gates = h@W_hh^T + pred*W_ih^T + (b_ih+b_hh)
//                      c = sig(f)*c + sig(i)*tanh(g); h = sig(o)*tanh(c)
//                      pred = h@W_out^T + b_out  (fed back as next x)
// Strategy: 128 per-step MFMA GEMM kernels (bf16 inputs, fp32 acc/state),
// cell update fused into GEMM epilogue via gate-colocated n-tiles.

#define HH 1024
#define BB 4096
#define TT 128

#define BM 128   // batch rows per block
#define BJ 32    // j columns per block (x4 gates = 128 weight rows)
#define BKK 64   // K tile
#define LDSTR 72 // BKK + 8 pad (16B-aligned rows, 2-way-only read conflicts)

typedef __bf16 bf16;
typedef __bf16 v8bf __attribute__((ext_vector_type(8)));
typedef float f32x4 __attribute__((ext_vector_type(4)));

__device__ __forceinline__ float fast_sigmoid(float x) {
    return 1.0f / (1.0f + __expf(-x));
}
__device__ __forceinline__ float fast_tanh(float x) {
    // tanh(x) = 1 - 2/(e^{2x}+1); saturates correctly at +/-inf
    return 1.0f - 2.0f / (__expf(2.0f * x) + 1.0f);
}

// ---- Prologue kernels ------------------------------------------------------

// Reorder W_hh rows so each j-block's 128 rows (4 gates x 32 j) are
// contiguous, converting fp32->bf16. Also bias = b_ih + b_hh.
__global__ void prep_weights(const float* __restrict__ Whh,
                             const float* __restrict__ bih,
                             const float* __restrict__ bhh,
                             bf16* __restrict__ Wr,
                             float* __restrict__ bias) {
    int idx = blockIdx.x * blockDim.x + threadIdx.x;
    if (idx < 4 * HH * HH) {
        int k   = idx & (HH - 1);
        int row = idx >> 10;          // Wr row: jb*128 + g*32 + jj
        int jb  = row >> 7;
        int g   = (row >> 5) & 3;
        int jj  = row & 31;
        int srow = g * HH + jb * 32 + jj;
        Wr[idx] = (bf16)Whh[srow * HH + k];
    }
    if (idx < 4 * HH) bias[idx] = bih[idx] + bhh[idx];
}

__global__ void prep_h(const float* __restrict__ h0, bf16* __restrict__ hb) {
    int idx = blockIdx.x * blockDim.x + threadIdx.x;
    if (idx < BB * HH) hb[idx] = (bf16)h0[idx];
}

// predbuf[0][:] = 0 (x0 = zeros); predbuf[t>=1][:] = b_out (atomics add raw dots)
__global__ void prep_pred(float* __restrict__ predbuf, const float* __restrict__ b_out) {
    int idx = blockIdx.x * blockDim.x + threadIdx.x;
    if (idx < (TT + 1) * BB) predbuf[idx] = (idx < BB) ? 0.0f : b_out[0];
}

// ---- Per-step fused GEMM + cell update ------------------------------------

__global__ __launch_bounds__(256, 2)
void lstm_step(const bf16* __restrict__ hread, bf16* __restrict__ hwrite,
               const float* __restrict__ cin, float* __restrict__ cout,
               const bf16* __restrict__ Wr, const float* __restrict__ bias,
               const float* __restrict__ Wih, const float* __restrict__ Wout,
               const float* __restrict__ predbuf_r, float* __restrict__ predbuf_w) {
    __shared__ bf16 As[BM][LDSTR];   // h tile: batch x k
    __shared__ bf16 Bs[BM][LDSTR];   // weight tile: (4 gates x 32 j) x k

    const int tid   = threadIdx.x;
    const int lane  = tid & 63;
    const int w     = tid >> 6;
    const int waveM = w >> 1, waveN = w & 1;
    const int quad  = lane >> 4, l15 = lane & 15;

    const int jb     = blockIdx.x;       // 0..31 (j-block)
    const int blockB = blockIdx.y * BM;  // batch base

    f32x4 acc[4][4]; // [m-tile][gate]
#pragma unroll
    for (int mi = 0; mi < 4; mi++)
#pragma unroll
        for (int g = 0; g < 4; g++) acc[mi][g] = (f32x4){0.f, 0.f, 0.f, 0.f};

    const bf16* Asrc = hread + (size_t)blockB * HH;
    const bf16* Bsrc = Wr + (size_t)jb * 128 * HH;

    for (int k0 = 0; k0 < HH; k0 += BKK) {
        // stage 128x64 bf16 for A and B: 1024 16B vectors each, 4 per thread
#pragma unroll
        for (int it = 0; it < 4; it++) {
            int vi  = tid + it * 256;
            int row = vi >> 3;
            int col = (vi & 7) * 8;
            *(uint4*)&As[row][col] = *(const uint4*)(Asrc + row * HH + k0 + col);
            *(uint4*)&Bs[row][col] = *(const uint4*)(Bsrc + row * HH + k0 + col);
        }
        __syncthreads();
#pragma unroll
        for (int kk = 0; kk < 2; kk++) {
            v8bf a[4], b[4];
#pragma unroll
            for (int mi = 0; mi < 4; mi++)
                a[mi] = *(const v8bf*)&As[waveM * 64 + mi * 16 + l15][kk * 32 + quad * 8];
#pragma unroll
            for (int g = 0; g < 4; g++)
                b[g] = *(const v8bf*)&Bs[g * 32 + waveN * 16 + l15][kk * 32 + quad * 8];
#pragma unroll
            for (int mi = 0; mi < 4; mi++)
#pragma unroll
                for (int g = 0; g < 4; g++)
                    acc[mi][g] = __builtin_amdgcn_mfma_f32_16x16x32_bf16(
                        a[mi], b[g], acc[mi][g], 0, 0, 0);
        }
        __syncthreads();
    }

    // Epilogue: each lane's acc[mi][0..3][r] are gates i,f,g,o at the SAME
    // (batch, j):  batch = blockB + waveM*64 + mi*16 + quad*4 + r
    //              j     = jb*32 + waveN*16 + l15
    const int jj = jb * 32 + waveN * 16 + l15;
    float wih[4], bsv[4];
#pragma unroll
    for (int g = 0; g < 4; g++) {
        wih[g] = Wih[g * HH + jj];
        bsv[g] = bias[g * HH + jj];
    }
    const float wo = Wout[jj];

#pragma unroll
    for (int mi = 0; mi < 4; mi++) {
#pragma unroll
        for (int r = 0; r < 4; r++) {
            const int b = blockB + waveM * 64 + mi * 16 + quad * 4 + r;
            const float x = predbuf_r[b];  // pred_{t-1} (incl. b_out) or 0 at t=0
            const float gi = acc[mi][0][r] + x * wih[0] + bsv[0];
            const float gf = acc[mi][1][r] + x * wih[1] + bsv[1];
            const float gg = acc[mi][2][r] + x * wih[2] + bsv[2];
            const float go = acc[mi][3][r] + x * wih[3] + bsv[3];
            const float cn = fast_sigmoid(gf) * cin[(size_t)b * HH + jj]
                           + fast_sigmoid(gi) * fast_tanh(gg);
            cout[(size_t)b * HH + jj] = cn;
            const float hn = fast_sigmoid(go) * fast_tanh(cn);
            hwrite[(size_t)b * HH + jj] = (bf16)hn;
            // partial pred: reduce h*W_out over the 16 lanes of this quad
            float p = hn * wo;
            p += __shfl_xor(p, 1);
            p += __shfl_xor(p, 2);
            p += __shfl_xor(p, 4);
            p += __shfl_xor(p, 8);
            if (l15 == 0) atomicAdd(&predbuf_w[b], p);
        }
    }
}

// ---- Output transpose: out[b][t] = pred_t[b] ------------------------------

__global__ void write_out(const float* __restrict__ predbuf, float* __restrict__ out) {
    int idx = blockIdx.x * blockDim.x + threadIdx.x;
    if (idx < BB * TT) {
        int t = idx & (TT - 1);
        int b = idx >> 7;
        out[idx] = predbuf[(size_t)(t + 1) * BB + b];
    }
}

// ---- Host launch -----------------------------------------------------------

extern "C" void kernel_launch(void* const* d_in, const int* in_sizes, int n_in,
                              void* d_out, int out_size, void* d_ws, size_t ws_size,
                              hipStream_t stream) {
    const float* hidden = (const float*)d_in[0];
    const float* cell   = (const float*)d_in[1];
    const float* Wih    = (const float*)d_in[2];
    const float* Whh    = (const float*)d_in[3];
    const float* bih    = (const float*)d_in[4];
    const float* bhh    = (const float*)d_in[5];
    const float* Wout   = (const float*)d_in[6];
    const float* bout   = (const float*)d_in[7];
    float* out = (float*)d_out;

    char* ws = (char*)d_ws;
    bf16* Wr = (bf16*)ws;        ws += (size_t)4 * HH * HH * 2;   // 8 MB
    bf16* hb0 = (bf16*)ws;       ws += (size_t)BB * HH * 2;       // 8 MB
    bf16* hb1 = (bf16*)ws;       ws += (size_t)BB * HH * 2;       // 8 MB
    float* cbuf = (float*)ws;    ws += (size_t)BB * HH * 4;       // 16 MB
    float* bias = (float*)ws;    ws += (size_t)4 * HH * 4;        // 16 KB
    float* predbuf = (float*)ws; ws += (size_t)(TT + 1) * BB * 4; // 2.1 MB

    prep_weights<<<(4 * HH * HH + 255) / 256, 256, 0, stream>>>(Whh, bih, bhh, Wr, bias);
    prep_h<<<(BB * HH + 255) / 256, 256, 0, stream>>>(hidden, hb0);
    prep_pred<<<((TT + 1) * BB + 255) / 256, 256, 0, stream>>>(predbuf, bout);

    bf16* hb[2] = {hb0, hb1};
    for (int t = 0; t < TT; t++) {
        const bf16* hr = hb[t & 1];
        bf16* hw = hb[(t + 1) & 1];
        const float* ci = (t == 0) ? cell : cbuf;
        lstm_step<<<dim3(HH / BJ, BB / BM), 256, 0, stream>>>(
            hr, hw, ci, cbuf, Wr, bias, Wih, Wout,
            predbuf + (size_t)t * BB, predbuf + (size_t)(t + 1) * BB);
    }

    write_out<<<(BB * TT + 255) / 256, 256, 0, stream>>>(predbuf, out);
}

// Round 2
// 5764.914 us; speedup vs baseline: 1.1361x; 1.1361x over previous
//
#include <hip/hip_runtime.h>
#include <hip/hip_bf16.h>
#include <stdint.h>

// LSTM decoder: H=1024, B=4096, T=128, IN=1.
// R2: m97-style staging — __builtin_amdgcn_global_load_lds width=16 into an
// unpadded XOR-swizzled LDS tile; 4 blocks/CU; XCD-grouped j-blocks for
// weight L2 residency.

#define HH 1024
#define BB 4096
#define TT 128

#define BM 128   // batch rows per block
#define BJ 32    // j columns per block (x4 gates = 128 weight rows)
#define BKK 64   // K tile

typedef __bf16 bf16;
typedef __bf16 v8bf __attribute__((ext_vector_type(8)));
typedef float f32x4 __attribute__((ext_vector_type(4)));

__device__ __forceinline__ float fast_sigmoid(float x) {
    return 1.0f / (1.0f + __expf(-x));
}
__device__ __forceinline__ float fast_tanh(float x) {
    return 1.0f - 2.0f / (__expf(2.0f * x) + 1.0f);
}

// generic->AS1/AS3 pointer conversion via inttoptr (CK-style; low 32 bits of a
// generic LDS pointer are the LDS byte offset on gfx9+).
__device__ __forceinline__ void gload_lds16(const void* g, void* l) {
    __builtin_amdgcn_global_load_lds(
        (const __attribute__((address_space(1))) uint32_t*)(uintptr_t)g,
        (__attribute__((address_space(3))) uint32_t*)(uint32_t)(uintptr_t)l,
        16, 0, 0);
}

// ---- Prologue kernels ------------------------------------------------------

__global__ void prep_weights(const float* __restrict__ Whh,
                             const float* __restrict__ bih,
                             const float* __restrict__ bhh,
                             bf16* __restrict__ Wr,
                             float* __restrict__ bias) {
    int idx = blockIdx.x * blockDim.x + threadIdx.x;
    if (idx < 4 * HH * HH) {
        int k   = idx & (HH - 1);
        int row = idx >> 10;          // Wr row: jb*128 + g*32 + jj
        int jb  = row >> 7;
        int g   = (row >> 5) & 3;
        int jj  = row & 31;
        int srow = g * HH + jb * 32 + jj;
        Wr[idx] = (bf16)Whh[srow * HH + k];
    }
    if (idx < 4 * HH) bias[idx] = bih[idx] + bhh[idx];
}

__global__ void prep_h(const float* __restrict__ h0, bf16* __restrict__ hb) {
    int idx = blockIdx.x * blockDim.x + threadIdx.x;
    if (idx < BB * HH) hb[idx] = (bf16)h0[idx];
}

__global__ void prep_pred(float* __restrict__ predbuf, const float* __restrict__ b_out) {
    int idx = blockIdx.x * blockDim.x + threadIdx.x;
    if (idx < (TT + 1) * BB) predbuf[idx] = (idx < BB) ? 0.0f : b_out[0];
}

// ---- Per-step fused GEMM + cell update ------------------------------------

__global__ __launch_bounds__(256, 4)
void lstm_step(const bf16* __restrict__ hread, bf16* __restrict__ hwrite,
               const float* __restrict__ cin, float* __restrict__ cout,
               const bf16* __restrict__ Wr, const float* __restrict__ bias,
               const float* __restrict__ Wih, const float* __restrict__ Wout,
               const float* __restrict__ predbuf_r, float* __restrict__ predbuf_w) {
    // unpadded, XOR-swizzled: physical 16B-chunk = logical_chunk ^ (row & 7)
    __shared__ bf16 As[BM][BKK];   // h tile: batch x k       (16 KB)
    __shared__ bf16 Bs[BM][BKK];   // weights: (4g x 32j) x k (16 KB)

    const int tid   = threadIdx.x;
    const int lane  = tid & 63;
    const int w     = tid >> 6;
    const int waveM = w >> 1, waveN = w & 1;
    const int quad  = lane >> 4, l15 = lane & 15;

    // XCD-grouped decode: presumed blockID%8 -> XCD. Each XCD sees 4 jb values
    // (1 MB of Wr, L2-resident across batch-blocks and across step kernels).
    const int bid    = blockIdx.x;
    const int jb     = (bid & 7) * 4 + ((bid >> 3) & 3); // 0..31
    const int blockB = (bid >> 5) * BM;                  // batch base

    f32x4 acc[4][4]; // [m-tile][gate]
#pragma unroll
    for (int mi = 0; mi < 4; mi++)
#pragma unroll
        for (int g = 0; g < 4; g++) acc[mi][g] = (f32x4){0.f, 0.f, 0.f, 0.f};

    const bf16* Asrc = hread + (size_t)blockB * HH;
    const bf16* Bsrc = Wr + (size_t)jb * 128 * HH;

    // staging lane decode: within a 64-lane call, lane L -> LDS row base+L>>3,
    // physical chunk L&7, which must hold global chunk (L&7)^(L>>3).
    const int r8 = lane >> 3;        // 0..7
    const int gc = (lane & 7) ^ r8;  // swizzled global 16B-chunk index
    const int swr = l15 & 7;         // read-side swizzle key (row & 7)

    for (int k0 = 0; k0 < HH; k0 += BKK) {
        // each wave stages 32 rows of A and 32 rows of B: 4 calls each,
        // one call = 64 lanes x 16 B = 8 rows x 128 B
#pragma unroll
        for (int c2 = 0; c2 < 4; c2++) {
            const int rowb = w * 32 + c2 * 8;
            gload_lds16(Asrc + (size_t)(rowb + r8) * HH + k0 + gc * 8, &As[rowb][0]);
            gload_lds16(Bsrc + (size_t)(rowb + r8) * HH + k0 + gc * 8, &Bs[rowb][0]);
        }
        asm volatile("s_waitcnt vmcnt(0)" ::: "memory");
        __syncthreads();
#pragma unroll
        for (int kk = 0; kk < 2; kk++) {
            v8bf a[4], b[4];
            const int pch = ((kk * 4 + quad) ^ swr) * 8;
#pragma unroll
            for (int mi = 0; mi < 4; mi++)
                a[mi] = *(const v8bf*)&As[waveM * 64 + mi * 16 + l15][pch];
#pragma unroll
            for (int g = 0; g < 4; g++)
                b[g] = *(const v8bf*)&Bs[g * 32 + waveN * 16 + l15][pch];
#pragma unroll
            for (int mi = 0; mi < 4; mi++)
#pragma unroll
                for (int g = 0; g < 4; g++)
                    acc[mi][g] = __builtin_amdgcn_mfma_f32_16x16x32_bf16(
                        a[mi], b[g], acc[mi][g], 0, 0, 0);
        }
        __syncthreads();
    }

    // Epilogue: acc[mi][0..3][r] = gates i,f,g,o at the SAME (batch, j):
    //   batch = blockB + waveM*64 + mi*16 + quad*4 + r
    //   j     = jb*32 + waveN*16 + l15
    const int jj = jb * 32 + waveN * 16 + l15;
    float wih[4], bsv[4];
#pragma unroll
    for (int g = 0; g < 4; g++) {
        wih[g] = Wih[g * HH + jj];
        bsv[g] = bias[g * HH + jj];
    }
    const float wo = Wout[jj];

#pragma unroll
    for (int mi = 0; mi < 4; mi++) {
#pragma unroll
        for (int r = 0; r < 4; r++) {
            const int b = blockB + waveM * 64 + mi * 16 + quad * 4 + r;
            const float x = predbuf_r[b];  // pred_{t-1} (incl. b_out) or 0 at t=0
            const float gi = acc[mi][0][r] + x * wih[0] + bsv[0];
            const float gf = acc[mi][1][r] + x * wih[1] + bsv[1];
            const float gg = acc[mi][2][r] + x * wih[2] + bsv[2];
            const float go = acc[mi][3][r] + x * wih[3] + bsv[3];
            const float cn = fast_sigmoid(gf) * cin[(size_t)b * HH + jj]
                           + fast_sigmoid(gi) * fast_tanh(gg);
            cout[(size_t)b * HH + jj] = cn;
            const float hn = fast_sigmoid(go) * fast_tanh(cn);
            hwrite[(size_t)b * HH + jj] = (bf16)hn;
            float p = hn * wo;
            p += __shfl_xor(p, 1);
            p += __shfl_xor(p, 2);
            p += __shfl_xor(p, 4);
            p += __shfl_xor(p, 8);
            if (l15 == 0) atomicAdd(&predbuf_w[b], p);
        }
    }
}

// ---- Output transpose: out[b][t] = pred_t[b] ------------------------------

__global__ void write_out(const float* __restrict__ predbuf, float* __restrict__ out) {
    int idx = blockIdx.x * blockDim.x + threadIdx.x;
    if (idx < BB * TT) {
        int t = idx & (TT - 1);
        int b = idx >> 7;
        out[idx] = predbuf[(size_t)(t + 1) * BB + b];
    }
}

// ---- Host launch -----------------------------------------------------------

extern "C" void kernel_launch(void* const* d_in, const int* in_sizes, int n_in,
                              void* d_out, int out_size, void* d_ws, size_t ws_size,
                              hipStream_t stream) {
    const float* hidden = (const float*)d_in[0];
    const float* cell   = (const float*)d_in[1];
    const float* Wih    = (const float*)d_in[2];
    const float* Whh    = (const float*)d_in[3];
    const float* bih    = (const float*)d_in[4];
    const float* bhh    = (const float*)d_in[5];
    const float* Wout   = (const float*)d_in[6];
    const float* bout   = (const float*)d_in[7];
    float* out = (float*)d_out;

    char* ws = (char*)d_ws;
    bf16* Wr = (bf16*)ws;        ws += (size_t)4 * HH * HH * 2;   // 8 MB
    bf16* hb0 = (bf16*)ws;       ws += (size_t)BB * HH * 2;       // 8 MB
    bf16* hb1 = (bf16*)ws;       ws += (size_t)BB * HH * 2;       // 8 MB
    float* cbuf = (float*)ws;    ws += (size_t)BB * HH * 4;       // 16 MB
    float* bias = (float*)ws;    ws += (size_t)4 * HH * 4;        // 16 KB
    float* predbuf = (float*)ws; ws += (size_t)(TT + 1) * BB * 4; // 2.1 MB

    prep_weights<<<(4 * HH * HH + 255) / 256, 256, 0, stream>>>(Whh, bih, bhh, Wr, bias);
    prep_h<<<(BB * HH + 255) / 256, 256, 0, stream>>>(hidden, hb0);
    prep_pred<<<((TT + 1) * BB + 255) / 256, 256, 0, stream>>>(predbuf, bout);

    bf16* hb[2] = {hb0, hb1};
    for (int t = 0; t < TT; t++) {
        const bf16* hr = hb[t & 1];
        bf16* hw = hb[(t + 1) & 1];
        const float* ci = (t == 0) ? cell : cbuf;
        lstm_step<<<(HH / BJ) * (BB / BM), 256, 0, stream>>>(
            hr, hw, ci, cbuf, Wr, bias, Wih, Wout,
            predbuf + (size_t)t * BB, predbuf + (size_t)(t + 1) * BB);
    }

    write_out<<<(BB * TT + 255) / 256, 256, 0, stream>>>(predbuf, out);
}